// Round 2
// baseline (2890.634 us; speedup 1.0000x reference)
//
#include <hip/hip_runtime.h>
#include <hip/hip_bf16.h>

typedef unsigned short u16;
typedef __bf16  bf16x8 __attribute__((ext_vector_type(8)));
typedef float   f32x4  __attribute__((ext_vector_type(4)));

__device__ __constant__ float NF4C[16] = {
    -1.0f, -0.6961928009986877f, -0.5250730514526367f, -0.39491748809814453f,
    -0.28444138169288635f, -0.18477343022823334f, -0.09105003625154495f, 0.0f,
    0.07958029955625534f, 0.16093020141124725f, 0.24611230194568634f,
    0.33791524171829224f, 0.44070982933044434f, 0.5626170039176941f,
    0.7229568362236023f, 1.0f };

__device__ __forceinline__ u16 f2bf(float f) {
    union { float f; unsigned u; } v; v.f = f;
    unsigned r = v.u + 0x7FFFu + ((v.u >> 16) & 1u);
    return (u16)(r >> 16);
}
__device__ __forceinline__ float bf2f(u16 b) {
    union { unsigned u; float f; } v; v.u = ((unsigned)b) << 16;
    return v.f;
}

// async global->LDS, 16 bytes per lane (global_load_lds_dwordx4).
// HW semantics: LDS dest = wave-uniform base + lane*16. All our staging
// pointers are (base + lane*16) within each wave, matching.
__device__ __forceinline__ void gl2lds16(const void* g, void* l) {
    __builtin_amdgcn_global_load_lds(
        (__attribute__((address_space(1))) void*)g,
        (__attribute__((address_space(3))) void*)l,
        16, 0, 0);
}

// ---------------- cast x fp32 -> bf16, 8 elems/thread ----------------
__global__ __launch_bounds__(256) void cast_f32_bf16(
    const float* __restrict__ in, u16* __restrict__ out, int n8) {
    int i = blockIdx.x * 256 + threadIdx.x;
    if (i >= n8) return;
    const float4* p = (const float4*)in + (size_t)i * 2;
    float4 a = p[0], b = p[1];
    union { u16 u[8]; uint4 v; } r;
    r.u[0] = f2bf(a.x); r.u[1] = f2bf(a.y); r.u[2] = f2bf(a.z); r.u[3] = f2bf(a.w);
    r.u[4] = f2bf(b.x); r.u[5] = f2bf(b.y); r.u[6] = f2bf(b.z); r.u[7] = f2bf(b.w);
    ((uint4*)out)[i] = r.v;
}

// ---------------- NF4 dequant: int32 codes -> bf16, 8 elems/thread ----------
__global__ __launch_bounds__(256) void dequant_nf4(
    const int* __restrict__ q, const float* __restrict__ s,
    u16* __restrict__ w, int I, int spr) {
    __shared__ float tab[16];
    if (threadIdx.x < 16) tab[threadIdx.x] = NF4C[threadIdx.x];
    __syncthreads();
    int col = (blockIdx.x * 256 + threadIdx.x) * 8;
    if (col >= I) return;
    int row = blockIdx.y;
    size_t base = (size_t)row * I + col;
    int4 c0 = *(const int4*)(q + base);
    int4 c1 = *(const int4*)(q + base + 4);
    float sc = s[(size_t)row * spr + (col >> 6)];
    union { u16 u[8]; uint4 v; } r;
    r.u[0] = f2bf(tab[c0.x & 15] * sc);
    r.u[1] = f2bf(tab[c0.y & 15] * sc);
    r.u[2] = f2bf(tab[c0.z & 15] * sc);
    r.u[3] = f2bf(tab[c0.w & 15] * sc);
    r.u[4] = f2bf(tab[c1.x & 15] * sc);
    r.u[5] = f2bf(tab[c1.y & 15] * sc);
    r.u[6] = f2bf(tab[c1.z & 15] * sc);
    r.u[7] = f2bf(tab[c1.w & 15] * sc);
    *(uint4*)(w + base) = r.v;
}

// ---------------- bf16 GEMM, B transposed: C[M,N] = A[M,K] * B[N,K]^T -------
// 128x128 tile, BK=32, 4 waves, 4x4 x (16x16x32 bf16 MFMA) per wave.
// LDS layout: 8 sub-tiles of 16x32 per operand, each sub-tile stored in
// MFMA-fragment-linear order (64 lanes x 16B: row=lane&15, k=(lane>>4)*8).
// => both global_load_lds staging writes AND ds_read_b128 fragment reads are
// addr = base + lane*16: zero bank conflicts.
// EPI: 0 = store bf16; 1 = store bf16 silu(gate)*acc (gate may alias Cout);
//      2 = store fp32.
template<int EPI>
__global__ __launch_bounds__(256) void gemm_bt(
    const u16* __restrict__ A, const u16* __restrict__ B,
    void* Cout, const u16* gate, int K, int ldc) {
    __shared__ u16 lA[128 * 32];   // 8 KB = 8 sub-tiles x 512 u16
    __shared__ u16 lB[128 * 32];   // 8 KB

    const int tid  = threadIdx.x;
    const int lane = tid & 63;
    const int wv   = tid >> 6;
    const int bx   = blockIdx.x;   // N tile
    const int by   = blockIdx.y;   // M tile

    // staging: wave w, round r fills sub-tile st = w + 4r.
    // lane l loads global (row = st*16 + (l&15), k = (l>>4)*8 .. +8)  [16B]
    // into LDS st*1024B + l*16B.
    const int srow = wv * 16 + (lane & 15);
    const int scol = (lane >> 4) << 3;
    const u16* gA0 = A + (size_t)(by * 128 + srow) * K + scol;
    const u16* gA1 = gA0 + (size_t)64 * K;
    const u16* gB0 = B + (size_t)(bx * 128 + srow) * K + scol;
    const u16* gB1 = gB0 + (size_t)64 * K;
    u16* sA0 = lA + wv * 512 + lane * 8;  u16* sA1 = sA0 + 2048;
    u16* sB0 = lB + wv * 512 + lane * 8;  u16* sB1 = sB0 + 2048;

    // fragment base: wave's M sub-tiles start at (wv&1)*4, N at (wv>>1)*4
    const int wm = (wv & 1) << 6;
    const int wn = (wv >> 1) << 6;
    const u16* fA = lA + (wv & 1) * 4 * 512 + lane * 8;
    const u16* fB = lB + (wv >> 1) * 4 * 512 + lane * 8;

    f32x4 acc[4][4] = {};
    const int kIters = K >> 5;
    for (int kb = 0; kb < kIters; ++kb) {
        gl2lds16(gA0, sA0);
        gl2lds16(gA1, sA1);
        gl2lds16(gB0, sB0);
        gl2lds16(gB1, sB1);
        gA0 += 32; gA1 += 32; gB0 += 32; gB1 += 32;
        __syncthreads();   // compiler drains vmcnt(0) before barrier

        bf16x8 af[4], bfr[4];
        #pragma unroll
        for (int i = 0; i < 4; ++i) af[i]  = *(const bf16x8*)(fA + i * 512);
        #pragma unroll
        for (int j = 0; j < 4; ++j) bfr[j] = *(const bf16x8*)(fB + j * 512);
        #pragma unroll
        for (int i = 0; i < 4; ++i)
            #pragma unroll
            for (int j = 0; j < 4; ++j)
                acc[i][j] = __builtin_amdgcn_mfma_f32_16x16x32_bf16(
                    af[i], bfr[j], acc[i][j], 0, 0, 0);
        __syncthreads();   // protect LDS before next stage
    }

    // epilogue: D row = (lane>>4)*4 + reg, col = lane&15  (measured m89/m91)
    const int en = lane & 15;
    const int er = (lane >> 4) << 2;
    #pragma unroll
    for (int i = 0; i < 4; ++i) {
        int row0 = by * 128 + wm + i * 16 + er;
        #pragma unroll
        for (int j = 0; j < 4; ++j) {
            int col = bx * 128 + wn + j * 16 + en;
            #pragma unroll
            for (int r = 0; r < 4; ++r) {
                size_t idx = (size_t)(row0 + r) * ldc + col;
                float v = acc[i][j][r];
                if (EPI == 0) {
                    ((u16*)Cout)[idx] = f2bf(v);
                } else if (EPI == 1) {
                    float g = bf2f(gate[idx]);
                    float sg = g / (1.0f + __expf(-g));
                    ((u16*)Cout)[idx] = f2bf(sg * v);
                } else {
                    ((float*)Cout)[idx] = v;
                }
            }
        }
    }
}

extern "C" void kernel_launch(void* const* d_in, const int* in_sizes, int n_in,
                              void* d_out, int out_size, void* d_ws, size_t ws_size,
                              hipStream_t stream) {
    const float* x   = (const float*)d_in[0];
    const int*   w1q = (const int*)d_in[1];
    const float* w1s = (const float*)d_in[2];
    const int*   w2q = (const int*)d_in[3];
    const float* w2s = (const float*)d_in[4];
    const int*   w3q = (const int*)d_in[5];
    const float* w3s = (const float*)d_in[6];
    float* out = (float*)d_out;

    const int M = 4096, D = 4096, H = 11008;

    u16* xb = (u16*)d_ws;                    // M*D bf16      (33.5 MB)
    u16* wb = xb + (size_t)M * D;            // H*D bf16      (90.2 MB, reused w1/w2/w3)
    u16* hb = wb + (size_t)H * D;            // M*H bf16      (90.2 MB, gate then h)

    // 1. x -> bf16
    cast_f32_bf16<<<(M * D / 8 + 255) / 256, 256, 0, stream>>>(x, xb, M * D / 8);

    // 2-3. w1 dequant, gate = x @ w1^T
    dim3 dqg1((D / 8 + 255) / 256, H);
    dequant_nf4<<<dqg1, 256, 0, stream>>>(w1q, w1s, wb, D, D / 64);
    gemm_bt<0><<<dim3(H / 128, M / 128), 256, 0, stream>>>(xb, wb, hb, nullptr, D, H);

    // 4-5. w2 dequant, h = silu(gate) * (x @ w2^T)   (in-place over gate)
    dequant_nf4<<<dqg1, 256, 0, stream>>>(w2q, w2s, wb, D, D / 64);
    gemm_bt<1><<<dim3(H / 128, M / 128), 256, 0, stream>>>(xb, wb, hb, hb, D, H);

    // 6-7. w3 dequant, out = h @ w3^T (fp32)
    dim3 dqg3((H / 8 + 255) / 256, D);
    dequant_nf4<<<dqg3, 256, 0, stream>>>(w3q, w3s, wb, H, H / 64);
    gemm_bt<2><<<dim3(D / 128, M / 128), 256, 0, stream>>>(hb, wb, out, nullptr, H, D);
}

// Round 3
// 2345.622 us; speedup vs baseline: 1.2324x; 1.2324x over previous
//
#include <hip/hip_runtime.h>
#include <hip/hip_bf16.h>

typedef unsigned short u16;
typedef __bf16  bf16x8 __attribute__((ext_vector_type(8)));
typedef float   f32x4  __attribute__((ext_vector_type(4)));

__device__ __constant__ float NF4C[16] = {
    -1.0f, -0.6961928009986877f, -0.5250730514526367f, -0.39491748809814453f,
    -0.28444138169288635f, -0.18477343022823334f, -0.09105003625154495f, 0.0f,
    0.07958029955625534f, 0.16093020141124725f, 0.24611230194568634f,
    0.33791524171829224f, 0.44070982933044434f, 0.5626170039176941f,
    0.7229568362236023f, 1.0f };

__device__ __forceinline__ u16 f2bf(float f) {
    union { float f; unsigned u; } v; v.f = f;
    unsigned r = v.u + 0x7FFFu + ((v.u >> 16) & 1u);
    return (u16)(r >> 16);
}
__device__ __forceinline__ float bf2f(u16 b) {
    union { unsigned u; float f; } v; v.u = ((unsigned)b) << 16;
    return v.f;
}

// async global->LDS, 16 bytes per lane (global_load_lds_dwordx4).
// HW: LDS dest = wave-uniform base + lane*16. Our staging ptrs are exactly
// base + lane*16 within each wave.
__device__ __forceinline__ void gl2lds16(const void* g, void* l) {
    __builtin_amdgcn_global_load_lds(
        (__attribute__((address_space(1))) void*)g,
        (__attribute__((address_space(3))) void*)l,
        16, 0, 0);
}

// ---------------- cast x fp32 -> bf16, 8 elems/thread ----------------
__global__ __launch_bounds__(256) void cast_f32_bf16(
    const float* __restrict__ in, u16* __restrict__ out, int n8) {
    int i = blockIdx.x * 256 + threadIdx.x;
    if (i >= n8) return;
    const float4* p = (const float4*)in + (size_t)i * 2;
    float4 a = p[0], b = p[1];
    union { u16 u[8]; uint4 v; } r;
    r.u[0] = f2bf(a.x); r.u[1] = f2bf(a.y); r.u[2] = f2bf(a.z); r.u[3] = f2bf(a.w);
    r.u[4] = f2bf(b.x); r.u[5] = f2bf(b.y); r.u[6] = f2bf(b.z); r.u[7] = f2bf(b.w);
    ((uint4*)out)[i] = r.v;
}

// ---------------- NF4 dequant: int32 codes -> bf16, 8 elems/thread ----------
__global__ __launch_bounds__(256) void dequant_nf4(
    const int* __restrict__ q, const float* __restrict__ s,
    u16* __restrict__ w, int I, int spr) {
    __shared__ float tab[16];
    if (threadIdx.x < 16) tab[threadIdx.x] = NF4C[threadIdx.x];
    __syncthreads();
    int col = (blockIdx.x * 256 + threadIdx.x) * 8;
    if (col >= I) return;
    int row = blockIdx.y;
    size_t base = (size_t)row * I + col;
    int4 c0 = *(const int4*)(q + base);
    int4 c1 = *(const int4*)(q + base + 4);
    float sc = s[(size_t)row * spr + (col >> 6)];
    union { u16 u[8]; uint4 v; } r;
    r.u[0] = f2bf(tab[c0.x & 15] * sc);
    r.u[1] = f2bf(tab[c0.y & 15] * sc);
    r.u[2] = f2bf(tab[c0.z & 15] * sc);
    r.u[3] = f2bf(tab[c0.w & 15] * sc);
    r.u[4] = f2bf(tab[c1.x & 15] * sc);
    r.u[5] = f2bf(tab[c1.y & 15] * sc);
    r.u[6] = f2bf(tab[c1.z & 15] * sc);
    r.u[7] = f2bf(tab[c1.w & 15] * sc);
    *(uint4*)(w + base) = r.v;
}

// ---------------- bf16 GEMM, B transposed: C[M,N] = A[M,K] * B[N,K]^T -------
// 128x128 tile, BK=32, 4 waves, 4x4 x (16x16x32 bf16 MFMA) per wave.
//
// LDS layout: per operand, 8 sub-tiles of 16 rows x 32 k, 1 KB each.
// Within a sub-tile, 16B slot l holds global (row r = l>>2,
// colq = (l&3) ^ f(r)), f(r) = (r>>1)&3.
//  - staging: lane-quad 4t..4t+3 reads one contiguous 64B row segment
//    (XOR permutes within the quad) -> full quad coalescing, and the LDS
//    write is base + lane*16 (global_load_lds requirement).
//  - fragment read: lane l needs (r=l&15, q=l>>4) -> slot 4r + (q^f(r));
//    bank-group residue hits each of 8 values exactly 2x per 16-lane
//    phase -> 2-way aliasing = free (m136).
// EPI: 0 = store bf16; 1 = store bf16 silu(gate)*acc (gate may alias Cout);
//      2 = store fp32.
template<int EPI>
__global__ __launch_bounds__(256) void gemm_bt(
    const u16* __restrict__ A, const u16* __restrict__ B,
    void* Cout, const u16* gate, int K, int ldc) {
    __shared__ u16 lA[128 * 32];   // 8 KB = 8 sub-tiles x 512 u16
    __shared__ u16 lB[128 * 32];   // 8 KB

    const int tid  = threadIdx.x;
    const int lane = tid & 63;
    const int wv   = tid >> 6;
    const int bx   = blockIdx.x;   // N tile
    const int by   = blockIdx.y;   // M tile

    // staging: wave wv fills sub-tile wv (rounds: +4). lane l covers
    // (row = l>>2, colq = (l&3) ^ f(l>>2)) of the sub-tile.
    const int sr = lane >> 2;
    const int sq = (lane & 3) ^ ((sr >> 1) & 3);
    const int srow = wv * 16 + sr;
    const int scol = sq << 3;
    const u16* gA0 = A + (size_t)(by * 128 + srow) * K + scol;
    const u16* gA1 = gA0 + (size_t)64 * K;
    const u16* gB0 = B + (size_t)(bx * 128 + srow) * K + scol;
    const u16* gB1 = gB0 + (size_t)64 * K;
    u16* sA0 = lA + wv * 512 + lane * 8;  u16* sA1 = sA0 + 2048;
    u16* sB0 = lB + wv * 512 + lane * 8;  u16* sB1 = sB0 + 2048;

    // fragment read: lane l wants (r=l&15, q=l>>4) -> slot 4r + (q^f(r))
    const int r16  = lane & 15;
    const int pq   = lane >> 4;
    const int slot = (r16 << 2) + (pq ^ ((r16 >> 1) & 3));
    const int wm = (wv & 1) << 6;
    const int wn = (wv >> 1) << 6;
    const u16* fA = lA + (wv & 1) * 2048 + slot * 8;
    const u16* fB = lB + (wv >> 1) * 2048 + slot * 8;

    f32x4 acc[4][4] = {};
    const int kIters = K >> 5;
    for (int kb = 0; kb < kIters; ++kb) {
        gl2lds16(gA0, sA0);
        gl2lds16(gA1, sA1);
        gl2lds16(gB0, sB0);
        gl2lds16(gB1, sB1);
        gA0 += 32; gA1 += 32; gB0 += 32; gB1 += 32;
        __syncthreads();   // compiler drains vmcnt(0) before barrier

        bf16x8 af[4], bfr[4];
        #pragma unroll
        for (int i = 0; i < 4; ++i) af[i]  = *(const bf16x8*)(fA + i * 512);
        #pragma unroll
        for (int j = 0; j < 4; ++j) bfr[j] = *(const bf16x8*)(fB + j * 512);
        #pragma unroll
        for (int i = 0; i < 4; ++i)
            #pragma unroll
            for (int j = 0; j < 4; ++j)
                acc[i][j] = __builtin_amdgcn_mfma_f32_16x16x32_bf16(
                    af[i], bfr[j], acc[i][j], 0, 0, 0);
        __syncthreads();   // protect LDS before next stage
    }

    // epilogue: D row = (lane>>4)*4 + reg, col = lane&15  (measured m89/m91)
    const int en = lane & 15;
    const int er = (lane >> 4) << 2;
    #pragma unroll
    for (int i = 0; i < 4; ++i) {
        int row0 = by * 128 + wm + i * 16 + er;
        #pragma unroll
        for (int j = 0; j < 4; ++j) {
            int col = bx * 128 + wn + j * 16 + en;
            #pragma unroll
            for (int r = 0; r < 4; ++r) {
                size_t idx = (size_t)(row0 + r) * ldc + col;
                float v = acc[i][j][r];
                if (EPI == 0) {
                    ((u16*)Cout)[idx] = f2bf(v);
                } else if (EPI == 1) {
                    float g = bf2f(gate[idx]);
                    float sg = g / (1.0f + __expf(-g));
                    ((u16*)Cout)[idx] = f2bf(sg * v);
                } else {
                    ((float*)Cout)[idx] = v;
                }
            }
        }
    }
}

extern "C" void kernel_launch(void* const* d_in, const int* in_sizes, int n_in,
                              void* d_out, int out_size, void* d_ws, size_t ws_size,
                              hipStream_t stream) {
    const float* x   = (const float*)d_in[0];
    const int*   w1q = (const int*)d_in[1];
    const float* w1s = (const float*)d_in[2];
    const int*   w2q = (const int*)d_in[3];
    const float* w2s = (const float*)d_in[4];
    const int*   w3q = (const int*)d_in[5];
    const float* w3s = (const float*)d_in[6];
    float* out = (float*)d_out;

    const int M = 4096, D = 4096, H = 11008;

    u16* xb = (u16*)d_ws;                    // M*D bf16      (33.5 MB)
    u16* wb = xb + (size_t)M * D;            // H*D bf16      (90.2 MB, reused w1/w2/w3)
    u16* hb = wb + (size_t)H * D;            // M*H bf16      (90.2 MB, gate then h)

    // 1. x -> bf16
    cast_f32_bf16<<<(M * D / 8 + 255) / 256, 256, 0, stream>>>(x, xb, M * D / 8);

    // 2-3. w1 dequant, gate = x @ w1^T
    dim3 dqg1((D / 8 + 255) / 256, H);
    dequant_nf4<<<dqg1, 256, 0, stream>>>(w1q, w1s, wb, D, D / 64);
    gemm_bt<0><<<dim3(H / 128, M / 128), 256, 0, stream>>>(xb, wb, hb, nullptr, D, H);

    // 4-5. w2 dequant, h = silu(gate) * (x @ w2^T)   (in-place over gate)
    dequant_nf4<<<dqg1, 256, 0, stream>>>(w2q, w2s, wb, D, D / 64);
    gemm_bt<1><<<dim3(H / 128, M / 128), 256, 0, stream>>>(xb, wb, hb, hb, D, H);

    // 6-7. w3 dequant, out = h @ w3^T (fp32)
    dim3 dqg3((H / 8 + 255) / 256, D);
    dequant_nf4<<<dqg3, 256, 0, stream>>>(w3q, w3s, wb, H, H / 64);
    gemm_bt<2><<<dim3(D / 128, M / 128), 256, 0, stream>>>(hb, wb, out, nullptr, H, D);
}

// Round 4
// 2134.647 us; speedup vs baseline: 1.3542x; 1.0988x over previous
//
#include <hip/hip_runtime.h>
#include <hip/hip_bf16.h>

typedef unsigned short u16;
typedef __bf16  bf16x8 __attribute__((ext_vector_type(8)));
typedef float   f32x4  __attribute__((ext_vector_type(4)));

__device__ __constant__ float NF4C[16] = {
    -1.0f, -0.6961928009986877f, -0.5250730514526367f, -0.39491748809814453f,
    -0.28444138169288635f, -0.18477343022823334f, -0.09105003625154495f, 0.0f,
    0.07958029955625534f, 0.16093020141124725f, 0.24611230194568634f,
    0.33791524171829224f, 0.44070982933044434f, 0.5626170039176941f,
    0.7229568362236023f, 1.0f };

__device__ __forceinline__ u16 f2bf(float f) {
    union { float f; unsigned u; } v; v.f = f;
    unsigned r = v.u + 0x7FFFu + ((v.u >> 16) & 1u);
    return (u16)(r >> 16);
}
__device__ __forceinline__ float bf2f(u16 b) {
    union { unsigned u; float f; } v; v.u = ((unsigned)b) << 16;
    return v.f;
}

// async global->LDS, 16 bytes per lane (global_load_lds_dwordx4).
// HW: LDS dest = wave-uniform base + lane*16. Our staging ptrs are exactly
// base + lane*16 within each wave.
__device__ __forceinline__ void gl2lds16(const void* g, void* l) {
    __builtin_amdgcn_global_load_lds(
        (__attribute__((address_space(1))) void*)g,
        (__attribute__((address_space(3))) void*)l,
        16, 0, 0);
}

// ---------------- cast x fp32 -> bf16, 8 elems/thread ----------------
__global__ __launch_bounds__(256) void cast_f32_bf16(
    const float* __restrict__ in, u16* __restrict__ out, int n8) {
    int i = blockIdx.x * 256 + threadIdx.x;
    if (i >= n8) return;
    const float4* p = (const float4*)in + (size_t)i * 2;
    float4 a = p[0], b = p[1];
    union { u16 u[8]; uint4 v; } r;
    r.u[0] = f2bf(a.x); r.u[1] = f2bf(a.y); r.u[2] = f2bf(a.z); r.u[3] = f2bf(a.w);
    r.u[4] = f2bf(b.x); r.u[5] = f2bf(b.y); r.u[6] = f2bf(b.z); r.u[7] = f2bf(b.w);
    ((uint4*)out)[i] = r.v;
}

// ---------------- NF4 dequant: int32 codes -> bf16, 8 elems/thread ----------
__global__ __launch_bounds__(256) void dequant_nf4(
    const int* __restrict__ q, const float* __restrict__ s,
    u16* __restrict__ w, int I, int spr) {
    __shared__ float tab[16];
    if (threadIdx.x < 16) tab[threadIdx.x] = NF4C[threadIdx.x];
    __syncthreads();
    int col = (blockIdx.x * 256 + threadIdx.x) * 8;
    if (col >= I) return;
    int row = blockIdx.y;
    size_t base = (size_t)row * I + col;
    int4 c0 = *(const int4*)(q + base);
    int4 c1 = *(const int4*)(q + base + 4);
    float sc = s[(size_t)row * spr + (col >> 6)];
    union { u16 u[8]; uint4 v; } r;
    r.u[0] = f2bf(tab[c0.x & 15] * sc);
    r.u[1] = f2bf(tab[c0.y & 15] * sc);
    r.u[2] = f2bf(tab[c0.z & 15] * sc);
    r.u[3] = f2bf(tab[c0.w & 15] * sc);
    r.u[4] = f2bf(tab[c1.x & 15] * sc);
    r.u[5] = f2bf(tab[c1.y & 15] * sc);
    r.u[6] = f2bf(tab[c1.z & 15] * sc);
    r.u[7] = f2bf(tab[c1.w & 15] * sc);
    *(uint4*)(w + base) = r.v;
}

// ---------------- bf16 GEMM, B transposed: C[M,N] = A[M,K] * B[N,K]^T -------
// 128x128 tile, BK=32, 4 waves, 4x4 x (16x16x32 bf16 MFMA) per wave.
//
// LDS: 8 sub-tiles of 16x32 per operand, fragment-linear + XOR swizzle
// (round 3): staging quad-coalesced, fragment reads 2-way = free. 0 conflicts.
//
// Block swizzle (round 4): flat id -> super-columns of CH=8 N-tiles x all
// M-tiles. Shrinks the resident working set from (6 A + 86 B) strips to
// (32 A + 8 B); with round-robin XCD placement each XCD pins ~1 B strip in
// its 4 MB L2. Attacks the measured 4.3x/11x HBM over-fetch (= staging
// latency, the MFMA stall).
//
// EPI: 0 = store bf16; 1 = store bf16 silu(gate)*acc (gate may alias Cout);
//      2 = store fp32.
template<int EPI>
__global__ __launch_bounds__(256, 4) void gemm_bt(
    const u16* __restrict__ A, const u16* __restrict__ B,
    void* Cout, const u16* gate, int K, int ldc) {
    __shared__ u16 lA[128 * 32];   // 8 KB = 8 sub-tiles x 512 u16
    __shared__ u16 lB[128 * 32];   // 8 KB

    const int tid  = threadIdx.x;
    const int lane = tid & 63;
    const int wv   = tid >> 6;

    // ---- chunked block swizzle ----
    const int NT = gridDim.x, MT = gridDim.y;
    int id    = blockIdx.y * NT + blockIdx.x;
    int per   = MT << 3;                 // 8 * MT
    int chunk = id / per;
    int rem   = id - chunk * per;
    int start = chunk << 3;
    int width = NT - start; if (width > 8) width = 8;
    const int bx = start + rem % width;  // N tile
    const int by = rem / width;          // M tile

    // staging: wave wv fills sub-tile wv (rounds: +4). lane l covers
    // (row = l>>2, colq = (l&3) ^ f(l>>2)) of the sub-tile.
    const int sr = lane >> 2;
    const int sq = (lane & 3) ^ ((sr >> 1) & 3);
    const int srow = wv * 16 + sr;
    const int scol = sq << 3;
    const u16* gA0 = A + (size_t)(by * 128 + srow) * K + scol;
    const u16* gA1 = gA0 + (size_t)64 * K;
    const u16* gB0 = B + (size_t)(bx * 128 + srow) * K + scol;
    const u16* gB1 = gB0 + (size_t)64 * K;
    u16* sA0 = lA + wv * 512 + lane * 8;  u16* sA1 = sA0 + 2048;
    u16* sB0 = lB + wv * 512 + lane * 8;  u16* sB1 = sB0 + 2048;

    // fragment read: lane l wants (r=l&15, q=l>>4) -> slot 4r + (q^f(r))
    const int r16  = lane & 15;
    const int pq   = lane >> 4;
    const int slot = (r16 << 2) + (pq ^ ((r16 >> 1) & 3));
    const int wm = (wv & 1) << 6;
    const int wn = (wv >> 1) << 6;
    const u16* fA = lA + (wv & 1) * 2048 + slot * 8;
    const u16* fB = lB + (wv >> 1) * 2048 + slot * 8;

    f32x4 acc[4][4] = {};
    const int kIters = K >> 5;
    for (int kb = 0; kb < kIters; ++kb) {
        gl2lds16(gA0, sA0);
        gl2lds16(gA1, sA1);
        gl2lds16(gB0, sB0);
        gl2lds16(gB1, sB1);
        gA0 += 32; gA1 += 32; gB0 += 32; gB1 += 32;
        __syncthreads();   // compiler drains vmcnt(0) before barrier

        bf16x8 af[4], bfr[4];
        #pragma unroll
        for (int i = 0; i < 4; ++i) af[i]  = *(const bf16x8*)(fA + i * 512);
        #pragma unroll
        for (int j = 0; j < 4; ++j) bfr[j] = *(const bf16x8*)(fB + j * 512);
        #pragma unroll
        for (int i = 0; i < 4; ++i)
            #pragma unroll
            for (int j = 0; j < 4; ++j)
                acc[i][j] = __builtin_amdgcn_mfma_f32_16x16x32_bf16(
                    af[i], bfr[j], acc[i][j], 0, 0, 0);
        __syncthreads();   // protect LDS before next stage
    }

    // epilogue: D row = (lane>>4)*4 + reg, col = lane&15  (measured m89/m91)
    const int en = lane & 15;
    const int er = (lane >> 4) << 2;
    #pragma unroll
    for (int i = 0; i < 4; ++i) {
        int row0 = by * 128 + wm + i * 16 + er;
        #pragma unroll
        for (int j = 0; j < 4; ++j) {
            int col = bx * 128 + wn + j * 16 + en;
            #pragma unroll
            for (int r = 0; r < 4; ++r) {
                size_t idx = (size_t)(row0 + r) * ldc + col;
                float v = acc[i][j][r];
                if (EPI == 0) {
                    ((u16*)Cout)[idx] = f2bf(v);
                } else if (EPI == 1) {
                    float g = bf2f(gate[idx]);
                    float sg = g / (1.0f + __expf(-g));
                    ((u16*)Cout)[idx] = f2bf(sg * v);
                } else {
                    ((float*)Cout)[idx] = v;
                }
            }
        }
    }
}

extern "C" void kernel_launch(void* const* d_in, const int* in_sizes, int n_in,
                              void* d_out, int out_size, void* d_ws, size_t ws_size,
                              hipStream_t stream) {
    const float* x   = (const float*)d_in[0];
    const int*   w1q = (const int*)d_in[1];
    const float* w1s = (const float*)d_in[2];
    const int*   w2q = (const int*)d_in[3];
    const float* w2s = (const float*)d_in[4];
    const int*   w3q = (const int*)d_in[5];
    const float* w3s = (const float*)d_in[6];
    float* out = (float*)d_out;

    const int M = 4096, D = 4096, H = 11008;

    u16* xb = (u16*)d_ws;                    // M*D bf16      (33.5 MB)
    u16* wb = xb + (size_t)M * D;            // H*D bf16      (90.2 MB, reused w1/w2/w3)
    u16* hb = wb + (size_t)H * D;            // M*H bf16      (90.2 MB, gate then h)

    // 1. x -> bf16
    cast_f32_bf16<<<(M * D / 8 + 255) / 256, 256, 0, stream>>>(x, xb, M * D / 8);

    // 2-3. w1 dequant, gate = x @ w1^T
    dim3 dqg1((D / 8 + 255) / 256, H);
    dequant_nf4<<<dqg1, 256, 0, stream>>>(w1q, w1s, wb, D, D / 64);
    gemm_bt<0><<<dim3(H / 128, M / 128), 256, 0, stream>>>(xb, wb, hb, nullptr, D, H);

    // 4-5. w2 dequant, h = silu(gate) * (x @ w2^T)   (in-place over gate)
    dequant_nf4<<<dqg1, 256, 0, stream>>>(w2q, w2s, wb, D, D / 64);
    gemm_bt<1><<<dim3(H / 128, M / 128), 256, 0, stream>>>(xb, wb, hb, hb, D, H);

    // 6-7. w3 dequant, out = h @ w3^T (fp32)
    dim3 dqg3((H / 8 + 255) / 256, D);
    dequant_nf4<<<dqg3, 256, 0, stream>>>(w3q, w3s, wb, H, H / 64);
    gemm_bt<2><<<dim3(D / 128, M / 128), 256, 0, stream>>>(hb, wb, out, nullptr, H, D);
}